// Round 9
// baseline (5481.354 us; speedup 1.0000x reference)
//
#include <hip/hip_runtime.h>
#include <hip/hip_fp16.h>

#define N_USERS 200000
#define N_ITEMS 100000
#define N_NODES 300000   // N_USERS + N_ITEMS
#define DIM 64
#define N_EDGES 5000000

#define SB_SHIFT 8
#define SB_ROWS  256                                  // rows per superbucket
#define NSB ((N_NODES + SB_ROWS - 1) / SB_ROWS)       // 1172
#define G1 512                                        // workgroups in hist/scatter
#define CHUNK ((N_EDGES + G1 - 1) / G1)               // 9766 edges per wg
#define RSHIFT 20
#define CMASK ((1u << RSHIFT) - 1)                    // col fits 19 bits
#define NBIN NSB                                      // col>>8 source bins

// ---------------------------------------------------------------------------
// pass 1: per-workgroup LDS histogram over dst superbuckets -> dense M[wg][sb]
// ---------------------------------------------------------------------------
__global__ __launch_bounds__(256) void k_hist(const int* __restrict__ rows,
                                              int* __restrict__ M) {
    __shared__ int h[NSB];
    int wg = blockIdx.x, tid = threadIdx.x;
    for (int i = tid; i < NSB; i += 256) h[i] = 0;
    __syncthreads();
    int s0 = wg * CHUNK, s1 = min(s0 + CHUNK, N_EDGES);
    for (int e = s0 + tid; e < s1; e += 256)
        atomicAdd(&h[rows[e] >> SB_SHIFT], 1);        // LDS atomic
    __syncthreads();
    for (int i = tid; i < NSB; i += 256) M[(size_t)wg * NSB + i] = h[i];
}

// ---------------------------------------------------------------------------
// pass 2a: one block per superbucket — exclusive scan of M[0..511][sb]
// ---------------------------------------------------------------------------
__global__ __launch_bounds__(256) void k_scan_cols(int* __restrict__ M,
                                                   int* __restrict__ colsums) {
    __shared__ int s[G1];
    int sb = blockIdx.x, tid = threadIdx.x;
    int v0 = M[(size_t)tid * NSB + sb];
    int v1 = M[(size_t)(tid + 256) * NSB + sb];
    s[tid] = v0; s[tid + 256] = v1;
    __syncthreads();
    for (int off = 1; off < G1; off <<= 1) {
        int a = (tid >= off) ? s[tid - off] : 0;
        int b = s[tid + 256 - off];
        __syncthreads();
        s[tid] += a; s[tid + 256] += b;
        __syncthreads();
    }
    M[(size_t)tid * NSB + sb] = s[tid] - v0;          // exclusive within column
    M[(size_t)(tid + 256) * NSB + sb] = s[tid + 256] - v1;
    if (tid == 255) colsums[sb] = s[G1 - 1];
}

// ---------------------------------------------------------------------------
// pass 2b: single block — exclusive scan of colsums -> sbbase; sentinel
// ---------------------------------------------------------------------------
__global__ __launch_bounds__(256) void k_scan_sb(const int* __restrict__ colsums,
                                                 int* __restrict__ sbbase) {
    __shared__ int s[256];
    __shared__ int carry;
    int tid = threadIdx.x;
    if (tid == 0) carry = 0;
    __syncthreads();
    for (int base = 0; base < NSB; base += 256) {
        int i = base + tid;
        int v = (i < NSB) ? colsums[i] : 0;
        s[tid] = v;
        __syncthreads();
        for (int off = 1; off < 256; off <<= 1) {
            int t = (tid >= off) ? s[tid - off] : 0;
            __syncthreads();
            s[tid] += t;
            __syncthreads();
        }
        if (i < NSB) sbbase[i] = carry + s[tid] - v;
        __syncthreads();
        if (tid == 255) carry += s[255];
        __syncthreads();
    }
    if (tid == 0) sbbase[NSB] = N_EDGES;
}

// ---------------------------------------------------------------------------
// pass 3: scatter edges to exact precomputed (wg,sb) runs. LDS cursors only.
// Entry: x = (localrow << 20) | col, y = weight bits.
// ---------------------------------------------------------------------------
__global__ __launch_bounds__(256) void k_scatter(const int* __restrict__ rows,
                                                 const int* __restrict__ cols,
                                                 const float* __restrict__ w,
                                                 const int* __restrict__ M,
                                                 const int* __restrict__ sbbase,
                                                 uint2* __restrict__ ent1) {
    __shared__ int cur[NSB];
    int wg = blockIdx.x, tid = threadIdx.x;
    for (int i = tid; i < NSB; i += 256)
        cur[i] = sbbase[i] + M[(size_t)wg * NSB + i];
    __syncthreads();
    int s0 = wg * CHUNK, s1 = min(s0 + CHUNK, N_EDGES);
    for (int e = s0 + tid; e < s1; e += 256) {
        int r = rows[e];
        int pos = atomicAdd(&cur[r >> SB_SHIFT], 1);  // LDS atomic
        ent1[pos] = make_uint2(((unsigned)(r & (SB_ROWS - 1)) << RSHIFT) |
                               (unsigned)cols[e],
                               __float_as_uint(w[e]));
    }
}

// ---------------------------------------------------------------------------
// pass 4: one block per dst superbucket — counting-sort its region by SOURCE
// bin (col>>8) so the pull sweeps src monotonically. Keeps localrow bits.
// ---------------------------------------------------------------------------
__global__ __launch_bounds__(256) void k_sort_col(const uint2* __restrict__ ent1,
                                                  uint2* __restrict__ ent2,
                                                  const int* __restrict__ sbbase) {
    __shared__ int hist[NBIN];
    __shared__ int part[256];
    __shared__ int cur[NBIN];
    int sb = blockIdx.x, tid = threadIdx.x;
    int beg = sbbase[sb], end = sbbase[sb + 1];
    for (int i = tid; i < NBIN; i += 256) hist[i] = 0;
    __syncthreads();
    for (int i = beg + tid; i < end; i += 256)
        atomicAdd(&hist[(ent1[i].x & CMASK) >> 8], 1);
    __syncthreads();
    // exclusive scan over NBIN: 256 threads x 5 serial slots (1280 >= 1172)
    int base_i = tid * 5;
    int run = 0, loc[5];
    #pragma unroll
    for (int j = 0; j < 5; ++j) {
        int idx = base_i + j;
        int v = (idx < NBIN) ? hist[idx] : 0;
        loc[j] = run; run += v;
    }
    part[tid] = run;
    __syncthreads();
    int pv = run;
    for (int off = 1; off < 256; off <<= 1) {
        int t = (tid >= off) ? part[tid - off] : 0;
        __syncthreads();
        part[tid] += t;
        __syncthreads();
    }
    int pex = part[tid] - pv;                         // exclusive thread prefix
    #pragma unroll
    for (int j = 0; j < 5; ++j) {
        int idx = base_i + j;
        if (idx < NBIN) cur[idx] = beg + pex + loc[j];
    }
    __syncthreads();
    for (int i = beg + tid; i < end; i += 256) {
        uint2 e = ent1[i];
        int pos = atomicAdd(&cur[(e.x & CMASK) >> 8], 1);
        ent2[pos] = e;                                // keep lr|col packing
    }
}

// ---------------------------------------------------------------------------
// init: A16 = fp16(concat(user,item))
// ---------------------------------------------------------------------------
__global__ void init_f16(const float4* __restrict__ user,
                         const float4* __restrict__ item,
                         uint2* __restrict__ A16) {
    int i = blockIdx.x * blockDim.x + threadIdx.x;
    const int n = N_NODES * (DIM / 4);
    if (i >= n) return;
    const int userN = N_USERS * (DIM / 4);
    float4 v = (i < userN) ? user[i] : item[i - userN];
    __half2 h01 = __floats2half2_rn(v.x, v.y);
    __half2 h23 = __floats2half2_rn(v.z, v.w);
    uint2 st;
    st.x = *reinterpret_cast<unsigned*>(&h01);
    st.y = *reinterpret_cast<unsigned*>(&h23);
    A16[i] = st;
}

__device__ __forceinline__ float2 h2f2u(unsigned u) {
    __half2 h = *reinterpret_cast<__half2*>(&u);
    return __half22float2(h);
}

// ---------------------------------------------------------------------------
// LDS-accumulator pull: one 512-thread block per 256-row dst bucket.
// Entries sorted by src bin -> all concurrent blocks sweep src in the same
// order -> sliding src window stays L2-resident (cross-block reuse).
// Quad-packed: quarter q = lane>>4 owns edge p0+4s+q; dpos = lane&15 owns
// dims 4*dpos..+3 (8B gather/lane; 16 lanes = full 128B row; one gather
// instruction = 4 edges). Accumulate via LDS atomicAdd with per-row dim
// rotation slot = lr*64 + ((d + lr) & 63) to spread banks.
// FINAL fuses out = (l0 + L1 + src(=L2) + acc)/4.
// ---------------------------------------------------------------------------
template <int FINAL>
__global__ __launch_bounds__(512, 4) void pull_lds(
        const uint2* __restrict__ src4,      // node row = 16 uint2 (f16)
        uint2* __restrict__ dst4,
        const int* __restrict__ sbbase,
        const uint2* __restrict__ ent,
        const float4* __restrict__ user4,    // node row = 16 float4
        const float4* __restrict__ item4,
        const uint2* __restrict__ L1,
        float4* __restrict__ out4) {
    __shared__ float acc[SB_ROWS * DIM];     // 64 KB
    int sb = blockIdx.x, tid = threadIdx.x;

    float4* accv = (float4*)acc;
    for (int i = tid; i < SB_ROWS * DIM / 4; i += 512)
        accv[i] = make_float4(0.f, 0.f, 0.f, 0.f);
    __syncthreads();

    int beg = sbbase[sb], end = sbbase[sb + 1];
    int wave = tid >> 6, lane = tid & 63;
    int q = lane >> 4, dpos = lane & 15;

    for (int p0 = beg + wave * 16; p0 < end; p0 += 128) {
        #pragma unroll
        for (int s = 0; s < 4; ++s) {
            int p = p0 + s * 4 + q;
            uint2 e = ent[min(p, end - 1)];
            float w = (p < end) ? __uint_as_float(e.y) : 0.0f;
            unsigned col = e.x & CMASK;
            unsigned lr  = e.x >> RSHIFT;
            uint2 v = src4[(size_t)col * 16 + dpos];
            float2 f01 = h2f2u(v.x), f23 = h2f2u(v.y);
            int rbase = (int)lr * DIM;
            int t0 = 4 * dpos + (int)lr;             // rotation base
            atomicAdd(&acc[rbase + ((t0 + 0) & 63)], w * f01.x);
            atomicAdd(&acc[rbase + ((t0 + 1) & 63)], w * f01.y);
            atomicAdd(&acc[rbase + ((t0 + 2) & 63)], w * f23.x);
            atomicAdd(&acc[rbase + ((t0 + 3) & 63)], w * f23.y);
        }
    }
    __syncthreads();

    int row0 = sb * SB_ROWS;
    for (int i = tid; i < SB_ROWS * 16; i += 512) {
        int r = i >> 4, dg = i & 15;
        int gr = row0 + r;
        if (gr >= N_NODES) break;                    // monotonic in i
        int rbase = r * DIM;
        int t0 = 4 * dg + r;
        float a0 = acc[rbase + ((t0 + 0) & 63)];
        float a1 = acc[rbase + ((t0 + 1) & 63)];
        float a2 = acc[rbase + ((t0 + 2) & 63)];
        float a3 = acc[rbase + ((t0 + 3) & 63)];
        size_t gi = (size_t)gr * 16 + dg;
        if (FINAL) {
            float4 l0 = (gr < N_USERS)
                        ? user4[gi]
                        : item4[(size_t)(gr - N_USERS) * 16 + dg];
            uint2 u1 = L1[gi];                       // L1
            uint2 u2 = src4[gi];                     // L2 (this pull's src)
            float2 b01 = h2f2u(u1.x), b23 = h2f2u(u1.y);
            float2 c01 = h2f2u(u2.x), c23 = h2f2u(u2.y);
            float4 rr;
            rr.x = (l0.x + b01.x + c01.x + a0) * 0.25f;
            rr.y = (l0.y + b01.y + c01.y + a1) * 0.25f;
            rr.z = (l0.z + b23.x + c23.x + a2) * 0.25f;
            rr.w = (l0.w + b23.y + c23.y + a3) * 0.25f;
            out4[gi] = rr;
        } else {
            __half2 h01 = __floats2half2_rn(a0, a1);
            __half2 h23 = __floats2half2_rn(a2, a3);
            uint2 st;
            st.x = *reinterpret_cast<unsigned*>(&h01);
            st.y = *reinterpret_cast<unsigned*>(&h23);
            dst4[gi] = st;
        }
    }
}

extern "C" void kernel_launch(void* const* d_in, const int* in_sizes, int n_in,
                              void* d_out, int out_size, void* d_ws, size_t ws_size,
                              hipStream_t stream) {
    const float* user_w = (const float*)d_in[0];
    const float* item_w = (const float*)d_in[1];
    const int*   eidx   = (const int*)d_in[2];
    const float* ew     = (const float*)d_in[3];

    const int* rows = eidx;             // edge_index[0] (destination)
    const int* cols = eidx + N_EDGES;   // edge_index[1] (source)

    float* out = (float*)d_out;

    // workspace layout (~160 MB)
    __half* A16   = (__half*)d_ws;                           // 38.4 MB
    __half* B16   = A16 + (size_t)N_NODES * DIM;             // 38.4 MB
    uint2*  ent1  = (uint2*)(B16 + (size_t)N_NODES * DIM);   // 40 MB (SB-grouped)
    uint2*  ent2  = ent1 + N_EDGES;                          // 40 MB (col-binned)
    int*    M       = (int*)(ent2 + N_EDGES);                // G1*NSB (2.4 MB)
    int*    colsums = M + (size_t)G1 * NSB;                  // NSB
    int*    sbbase  = colsums + NSB;                         // NSB+1

    const int node_vec_blocks = (N_NODES * (DIM / 4) + 255) / 256;

    // ---- build: dst-bucket grouping, then col-bin sort within bucket ----
    k_hist<<<G1, 256, 0, stream>>>(rows, M);
    k_scan_cols<<<NSB, 256, 0, stream>>>(M, colsums);
    k_scan_sb<<<1, 256, 0, stream>>>(colsums, sbbase);
    k_scatter<<<G1, 256, 0, stream>>>(rows, cols, ew, M, sbbase, ent1);
    k_sort_col<<<NSB, 256, 0, stream>>>(ent1, ent2, sbbase);

    // ---- layer-0 fp16 snapshot ----
    init_f16<<<node_vec_blocks, 256, 0, stream>>>(
        (const float4*)user_w, (const float4*)item_w, (uint2*)A16);

    // ---- 3 pull layers; #3 fuses the final combine ----
    pull_lds<0><<<NSB, 512, 0, stream>>>(
        (const uint2*)A16, (uint2*)B16, sbbase, ent2,
        nullptr, nullptr, nullptr, nullptr);                 // L1 = B16
    pull_lds<0><<<NSB, 512, 0, stream>>>(
        (const uint2*)B16, (uint2*)A16, sbbase, ent2,
        nullptr, nullptr, nullptr, nullptr);                 // L2 = A16
    pull_lds<1><<<NSB, 512, 0, stream>>>(
        (const uint2*)A16, nullptr, sbbase, ent2,
        (const float4*)user_w, (const float4*)item_w,
        (const uint2*)B16, (float4*)out);
}

// Round 10
// 590.437 us; speedup vs baseline: 9.2836x; 9.2836x over previous
//
#include <hip/hip_runtime.h>
#include <hip/hip_fp16.h>

#define N_USERS 200000
#define N_ITEMS 100000
#define N_NODES 300000   // N_USERS + N_ITEMS
#define DIM 64
#define N_EDGES 5000000

#define SB_SHIFT 9
#define SB_ROWS  512                                  // rows per superbucket
#define NSB ((N_NODES + SB_ROWS - 1) / SB_ROWS)       // 586
#define G1 512                                        // workgroups in hist/scatter
#define CHUNK ((N_EDGES + G1 - 1) / G1)               // 9766 edges per wg
#define RSHIFT 20
#define CMASK ((1u << RSHIFT) - 1)                    // col fits 19 bits

// ---------------------------------------------------------------------------
// pass 1: per-workgroup LDS histogram over superbuckets -> dense M[wg][sb].
// ---------------------------------------------------------------------------
__global__ __launch_bounds__(256) void k_hist(const int* __restrict__ rows,
                                              int* __restrict__ M) {
    __shared__ int h[NSB];
    int wg = blockIdx.x, tid = threadIdx.x;
    for (int i = tid; i < NSB; i += 256) h[i] = 0;
    __syncthreads();
    int s0 = wg * CHUNK, s1 = min(s0 + CHUNK, N_EDGES);
    for (int e = s0 + tid; e < s1; e += 256)
        atomicAdd(&h[rows[e] >> SB_SHIFT], 1);        // LDS atomic
    __syncthreads();
    for (int i = tid; i < NSB; i += 256) M[(size_t)wg * NSB + i] = h[i];
}

// ---------------------------------------------------------------------------
// pass 2a: one block per superbucket — exclusive scan of M[0..511][sb].
// ---------------------------------------------------------------------------
__global__ __launch_bounds__(256) void k_scan_cols(int* __restrict__ M,
                                                   int* __restrict__ colsums) {
    __shared__ int s[G1];
    int sb = blockIdx.x, tid = threadIdx.x;
    int v0 = M[(size_t)tid * NSB + sb];
    int v1 = M[(size_t)(tid + 256) * NSB + sb];
    s[tid] = v0; s[tid + 256] = v1;
    __syncthreads();
    for (int off = 1; off < G1; off <<= 1) {
        int a = (tid >= off) ? s[tid - off] : 0;
        int b = s[tid + 256 - off];
        __syncthreads();
        s[tid] += a; s[tid + 256] += b;
        __syncthreads();
    }
    M[(size_t)tid * NSB + sb] = s[tid] - v0;          // exclusive within column
    M[(size_t)(tid + 256) * NSB + sb] = s[tid + 256] - v1;
    if (tid == 255) colsums[sb] = s[G1 - 1];
}

// ---------------------------------------------------------------------------
// pass 2b: single block — exclusive scan of colsums -> sbbase; sentinels.
// ---------------------------------------------------------------------------
__global__ __launch_bounds__(256) void k_scan_sb(const int* __restrict__ colsums,
                                                 int* __restrict__ sbbase,
                                                 int* __restrict__ row_ptr) {
    __shared__ int s[256];
    __shared__ int carry;
    int tid = threadIdx.x;
    if (tid == 0) carry = 0;
    __syncthreads();
    for (int base = 0; base < NSB; base += 256) {
        int i = base + tid;
        int v = (i < NSB) ? colsums[i] : 0;
        s[tid] = v;
        __syncthreads();
        for (int off = 1; off < 256; off <<= 1) {
            int t = (tid >= off) ? s[tid - off] : 0;
            __syncthreads();
            s[tid] += t;
            __syncthreads();
        }
        if (i < NSB) sbbase[i] = carry + s[tid] - v;
        __syncthreads();
        if (tid == 255) carry += s[255];
        __syncthreads();
    }
    if (tid == 0) { sbbase[NSB] = N_EDGES; row_ptr[N_NODES] = N_EDGES; }
}

// ---------------------------------------------------------------------------
// pass 3: scatter edges to exact precomputed (wg,sb) runs. LDS cursors only.
// Entry: x = (localrow << 20) | col, y = weight bits.
// ---------------------------------------------------------------------------
__global__ __launch_bounds__(256) void k_scatter(const int* __restrict__ rows,
                                                 const int* __restrict__ cols,
                                                 const float* __restrict__ w,
                                                 const int* __restrict__ M,
                                                 const int* __restrict__ sbbase,
                                                 uint2* __restrict__ ent1) {
    __shared__ int cur[NSB];
    int wg = blockIdx.x, tid = threadIdx.x;
    for (int i = tid; i < NSB; i += 256)
        cur[i] = sbbase[i] + M[(size_t)wg * NSB + i];
    __syncthreads();
    int s0 = wg * CHUNK, s1 = min(s0 + CHUNK, N_EDGES);
    for (int e = s0 + tid; e < s1; e += 256) {
        int r = rows[e];
        int pos = atomicAdd(&cur[r >> SB_SHIFT], 1);  // LDS atomic
        ent1[pos] = make_uint2(((unsigned)(r & (SB_ROWS - 1)) << RSHIFT) |
                               (unsigned)cols[e],
                               __float_as_uint(w[e]));
    }
}

// ---------------------------------------------------------------------------
// pass 4: one block per superbucket — counting-sort its L2-resident region
// by local row; emit row-sorted ent2 and row_ptr.
// ---------------------------------------------------------------------------
__global__ __launch_bounds__(256) void k_sort_sb(const uint2* __restrict__ ent1,
                                                 uint2* __restrict__ ent2,
                                                 const int* __restrict__ sbbase,
                                                 int* __restrict__ row_ptr) {
    __shared__ int s[SB_ROWS];
    __shared__ int cur[SB_ROWS];
    int sb = blockIdx.x, tid = threadIdx.x;
    int beg = sbbase[sb], end = sbbase[sb + 1];
    s[tid] = 0; s[tid + 256] = 0;
    __syncthreads();
    for (int i = beg + tid; i < end; i += 256)
        atomicAdd(&s[ent1[i].x >> RSHIFT], 1);        // LDS hist
    __syncthreads();
    int o0 = s[tid], o1 = s[tid + 256];
    for (int off = 1; off < SB_ROWS; off <<= 1) {
        int a = (tid >= off) ? s[tid - off] : 0;
        int b = s[tid + 256 - off];
        __syncthreads();
        s[tid] += a; s[tid + 256] += b;
        __syncthreads();
    }
    int b0 = beg + s[tid] - o0;                       // exclusive begins
    int b1 = beg + s[tid + 256] - o1;
    cur[tid] = b0; cur[tid + 256] = b1;
    int gr0 = sb * SB_ROWS + tid, gr1 = gr0 + 256;
    if (gr0 < N_NODES) row_ptr[gr0] = b0;
    if (gr1 < N_NODES) row_ptr[gr1] = b1;
    __syncthreads();
    for (int i = beg + tid; i < end; i += 256) {
        uint2 e = ent1[i];
        int pos = atomicAdd(&cur[e.x >> RSHIFT], 1);  // LDS cursor
        ent2[pos] = make_uint2(e.x & CMASK, e.y);
    }
}

// ---------------------------------------------------------------------------
// init: A16 = fp16(concat(user,item))
// ---------------------------------------------------------------------------
__global__ void init_f16(const float4* __restrict__ user,
                         const float4* __restrict__ item,
                         uint2* __restrict__ A16) {
    int i = blockIdx.x * blockDim.x + threadIdx.x;
    const int n = N_NODES * (DIM / 4);
    if (i >= n) return;
    const int userN = N_USERS * (DIM / 4);
    float4 v = (i < userN) ? user[i] : item[i - userN];
    __half2 h01 = __floats2half2_rn(v.x, v.y);
    __half2 h23 = __floats2half2_rn(v.z, v.w);
    uint2 st;
    st.x = *reinterpret_cast<unsigned*>(&h01);
    st.y = *reinterpret_cast<unsigned*>(&h23);
    A16[i] = st;
}

__device__ __forceinline__ float2 h2f2u(unsigned u) {
    __half2 h = *reinterpret_cast<__half2*>(&u);
    return __half22float2(h);
}

// ---------------------------------------------------------------------------
// tiered quad-packed pull: one wave per node; q = lane>>4 owns SLOTS
// consecutive edge slots; dpos = lane&15 owns dims 4*dpos..+3 (8B/lane,
// 16 lanes = 128B row; one gather instruction = 4 edges). Degree is
// wave-uniform, so tier selection (deg<=16: 4 slots; deg<=32: 8 slots;
// else chunked loop) has NO divergence — and for 99.99% of nodes the
// entry-load -> gather chain executes exactly ONCE (no loop-carried
// latency chain). Branchless weight-zero clamp for tails.
// ---------------------------------------------------------------------------
template <int SLOTS>
__device__ __forceinline__ void gather_chunk(
        const uint2* __restrict__ src4, const uint2* __restrict__ ent,
        int p0, int end, int q, int dpos,
        float& a0, float& a1, float& a2, float& a3) {
    unsigned cols[SLOTS];
    float ws[SLOTS];
    #pragma unroll
    for (int i = 0; i < SLOTS; ++i) {
        int p = p0 + SLOTS * q + i;
        uint2 e = ent[min(p, end - 1)];
        cols[i] = e.x;
        ws[i] = (p < end) ? __uint_as_float(e.y) : 0.0f;
    }
    uint2 vs[SLOTS];
    #pragma unroll
    for (int i = 0; i < SLOTS; ++i)
        vs[i] = src4[(size_t)cols[i] * 16 + dpos];
    #pragma unroll
    for (int i = 0; i < SLOTS; ++i) {
        float2 f01 = h2f2u(vs[i].x);
        float2 f23 = h2f2u(vs[i].y);
        a0 = fmaf(ws[i], f01.x, a0);
        a1 = fmaf(ws[i], f01.y, a1);
        a2 = fmaf(ws[i], f23.x, a2);
        a3 = fmaf(ws[i], f23.y, a3);
    }
}

template <int FINAL>
__global__ void pull_tier(const uint2* __restrict__ src4,   // node row = 16 uint2
                          uint2* __restrict__ dst4,
                          const int* __restrict__ row_ptr,
                          const uint2* __restrict__ ent,
                          const float4* __restrict__ user4,  // node row = 16 float4
                          const float4* __restrict__ item4,
                          const uint2* __restrict__ L1,
                          const uint2* __restrict__ L2,
                          float4* __restrict__ out4) {
    int node = blockIdx.x * (blockDim.x >> 6) + (threadIdx.x >> 6);
    int lane = threadIdx.x & 63;
    if (node >= N_NODES) return;
    int q = lane >> 4;                 // quarter 0..3
    int dpos = lane & 15;              // dim group (4 dims)

    int beg = row_ptr[node];
    int end = row_ptr[node + 1];
    int deg = end - beg;

    float a0 = 0.0f, a1 = 0.0f, a2 = 0.0f, a3 = 0.0f;
    if (deg > 0) {
        if (deg <= 16) {
            gather_chunk<4>(src4, ent, beg, end, q, dpos, a0, a1, a2, a3);
        } else if (deg <= 32) {
            gather_chunk<8>(src4, ent, beg, end, q, dpos, a0, a1, a2, a3);
        } else {
            int p0 = beg;
            for (; p0 + 32 <= end; p0 += 32)
                gather_chunk<8>(src4, ent, p0, end, q, dpos, a0, a1, a2, a3);
            if (p0 < end)
                gather_chunk<8>(src4, ent, p0, end, q, dpos, a0, a1, a2, a3);
        }
    }

    // reduce across quarters (lane bits 4 and 5)
    a0 += __shfl_xor(a0, 16); a0 += __shfl_xor(a0, 32);
    a1 += __shfl_xor(a1, 16); a1 += __shfl_xor(a1, 32);
    a2 += __shfl_xor(a2, 16); a2 += __shfl_xor(a2, 32);
    a3 += __shfl_xor(a3, 16); a3 += __shfl_xor(a3, 32);

    if (q == 0) {
        size_t gi = (size_t)node * 16 + dpos;
        if (FINAL) {
            float4 l0 = (node < N_USERS)
                        ? user4[gi]
                        : item4[(size_t)(node - N_USERS) * 16 + dpos];
            uint2 u1 = L1[gi], u2 = L2[gi];
            float2 b01 = h2f2u(u1.x), b23 = h2f2u(u1.y);
            float2 c01 = h2f2u(u2.x), c23 = h2f2u(u2.y);
            float4 r;
            r.x = (l0.x + b01.x + c01.x + a0) * 0.25f;
            r.y = (l0.y + b01.y + c01.y + a1) * 0.25f;
            r.z = (l0.z + b23.x + c23.x + a2) * 0.25f;
            r.w = (l0.w + b23.y + c23.y + a3) * 0.25f;
            out4[gi] = r;
        } else {
            __half2 h01 = __floats2half2_rn(a0, a1);
            __half2 h23 = __floats2half2_rn(a2, a3);
            uint2 st;
            st.x = *reinterpret_cast<unsigned*>(&h01);
            st.y = *reinterpret_cast<unsigned*>(&h23);
            dst4[gi] = st;
        }
    }
}

extern "C" void kernel_launch(void* const* d_in, const int* in_sizes, int n_in,
                              void* d_out, int out_size, void* d_ws, size_t ws_size,
                              hipStream_t stream) {
    const float* user_w = (const float*)d_in[0];
    const float* item_w = (const float*)d_in[1];
    const int*   eidx   = (const int*)d_in[2];
    const float* ew     = (const float*)d_in[3];

    const int* rows = eidx;             // edge_index[0] (destination)
    const int* cols = eidx + N_EDGES;   // edge_index[1] (source)

    float* out = (float*)d_out;

    // workspace layout (~159 MB)
    __half* A16   = (__half*)d_ws;                           // 38.4 MB
    __half* B16   = A16 + (size_t)N_NODES * DIM;             // 38.4 MB
    uint2*  ent1  = (uint2*)(B16 + (size_t)N_NODES * DIM);   // 40 MB (SB-grouped)
    uint2*  ent2  = ent1 + N_EDGES;                          // 40 MB (row-sorted)
    int*    M       = (int*)(ent2 + N_EDGES);                // G1*NSB (1.2 MB)
    int*    colsums = M + (size_t)G1 * NSB;                  // NSB
    int*    sbbase  = colsums + NSB;                         // NSB+1
    int*    row_ptr = sbbase + (NSB + 1);                    // N_NODES+1

    const int node_vec_blocks = (N_NODES * (DIM / 4) + 255) / 256;
    const int pull_blocks = (N_NODES + 3) / 4;               // 4 waves/block

    // ---- build row-sorted CSR: zero global atomics, dense writes ----
    k_hist<<<G1, 256, 0, stream>>>(rows, M);
    k_scan_cols<<<NSB, 256, 0, stream>>>(M, colsums);
    k_scan_sb<<<1, 256, 0, stream>>>(colsums, sbbase, row_ptr);
    k_scatter<<<G1, 256, 0, stream>>>(rows, cols, ew, M, sbbase, ent1);
    k_sort_sb<<<NSB, 256, 0, stream>>>(ent1, ent2, sbbase, row_ptr);

    // ---- layer-0 fp16 snapshot ----
    init_f16<<<node_vec_blocks, 256, 0, stream>>>(
        (const float4*)user_w, (const float4*)item_w, (uint2*)A16);

    // ---- 3 pull layers (2-buffer ping-pong); #3 fuses the final combine ----
    pull_tier<0><<<pull_blocks, 256, 0, stream>>>(
        (const uint2*)A16, (uint2*)B16, row_ptr, ent2,
        nullptr, nullptr, nullptr, nullptr, nullptr);            // L1 = B16
    pull_tier<0><<<pull_blocks, 256, 0, stream>>>(
        (const uint2*)B16, (uint2*)A16, row_ptr, ent2,
        nullptr, nullptr, nullptr, nullptr, nullptr);            // L2 = A16
    pull_tier<1><<<pull_blocks, 256, 0, stream>>>(
        (const uint2*)A16, nullptr, row_ptr, ent2,
        (const float4*)user_w, (const float4*)item_w,
        (const uint2*)B16, (const uint2*)A16, (float4*)out);
}